// Round 1
// baseline (255.831 us; speedup 1.0000x reference)
//
#include <hip/hip_runtime.h>

// RangeLoss: t' = conditional rewrite of target from preds (row-wise, col1
// depends on col2 of the same row), out = mean((preds - t')^2) over N*3 elems.
// Memory-bound: 201 MB read / 4 B write.

#define N_ROWS 8388608
#define ROWS_PER_THREAD 4
#define BLOCK 256
#define INV_TOTAL (1.0f / (3.0f * 8388608.0f))

__global__ void __launch_bounds__(BLOCK) rangeloss_kernel(
    const float4* __restrict__ preds4,
    const float4* __restrict__ target4,
    float* __restrict__ out)
{
    const int tid = blockIdx.x * BLOCK + threadIdx.x;
    float sum = 0.0f;

    if (tid < N_ROWS / ROWS_PER_THREAD) {
        const int base = tid * 3;  // 4 rows = 12 floats = 3 float4
        float4 pa = preds4[base + 0];
        float4 pb = preds4[base + 1];
        float4 pc = preds4[base + 2];
        float4 ta = target4[base + 0];
        float4 tb = target4[base + 1];
        float4 tc = target4[base + 2];

        float p[12] = {pa.x, pa.y, pa.z, pa.w,
                       pb.x, pb.y, pb.z, pb.w,
                       pc.x, pc.y, pc.z, pc.w};
        float t[12] = {ta.x, ta.y, ta.z, ta.w,
                       tb.x, tb.y, tb.z, tb.w,
                       tc.x, tc.y, tc.z, tc.w};

        #pragma unroll
        for (int r = 0; r < ROWS_PER_THREAD; ++r) {
            float p0 = p[3 * r + 0], p1 = p[3 * r + 1], p2 = p[3 * r + 2];
            float t0 = t[3 * r + 0], t1 = t[3 * r + 1], t2 = t[3 * r + 2];

            // t0: snap to p0 when confidently-correct (conditions mutually exclusive)
            if ((p0 < 0.1f && t0 == 0.0f) || (p0 > 0.9f && t0 == 1.0f)) t0 = p0;
            // t2: same rule
            if ((p2 < 0.1f && t2 == 0.0f) || (p2 > 0.9f && t2 == 1.0f)) t2 = p2;
            // t1: snap to p1 if p2>0.9 OR p1 within +/-2% of (original) t1
            bool in_range = (p1 * 1.02f > t1) && (p1 * 0.98f < t1);
            if (p2 > 0.9f || in_range) t1 = p1;

            float d0 = p0 - t0, d1 = p1 - t1, d2 = p2 - t2;
            sum += d0 * d0 + d1 * d1 + d2 * d2;
        }
        sum *= INV_TOTAL;  // pre-scale so final atomic sum is the mean
    }

    // wave-64 butterfly reduce
    #pragma unroll
    for (int off = 32; off > 0; off >>= 1)
        sum += __shfl_down(sum, off, 64);

    __shared__ float smem[BLOCK / 64];
    const int lane = threadIdx.x & 63;
    const int wave = threadIdx.x >> 6;
    if (lane == 0) smem[wave] = sum;
    __syncthreads();

    if (threadIdx.x == 0) {
        float s = smem[0] + smem[1] + smem[2] + smem[3];
        atomicAdd(out, s);  // device-scope by default; 8192 blocks -> negligible contention
    }
}

extern "C" void kernel_launch(void* const* d_in, const int* in_sizes, int n_in,
                              void* d_out, int out_size, void* d_ws, size_t ws_size,
                              hipStream_t stream)
{
    const float4* preds4  = (const float4*)d_in[0];
    const float4* target4 = (const float4*)d_in[1];
    float* out = (float*)d_out;

    // d_out is re-poisoned to 0xAA before every timed replay: zero it in-stream.
    hipMemsetAsync(out, 0, sizeof(float), stream);

    const int n_threads = N_ROWS / ROWS_PER_THREAD;        // 2097152
    const int n_blocks  = (n_threads + BLOCK - 1) / BLOCK; // 8192
    rangeloss_kernel<<<n_blocks, BLOCK, 0, stream>>>(preds4, target4, out);
}

// Round 2
// 232.190 us; speedup vs baseline: 1.1018x; 1.1018x over previous
//
#include <hip/hip_runtime.h>

// RangeLoss, coalesced-flat version.
// Semantics per flat element f (col = f % 3):
//   col 0/2: t' = ((p<0.1 && t==0) || (p>0.9 && t==1)) ? p : t
//   col 1  : t' = (p_next>0.9 || (p*1.02>t && p*0.98<t)) ? p : t   (p_next = preds[f+1], col2 same row)
// out = mean((p - t')^2).
// Memory-bound; the point of this version is perfectly coalesced float4 loads
// (prev version had 48B lane stride -> 3x L1/L2 transactions, 121us @ 10% HBM).

#define N3      25165824   // 8388608 * 3 floats
#define G4      6291456    // N3 / 4 float4s
#define BLOCK   256
#define UNROLL  4
#define INV_TOTAL (1.0f / 25165824.0f)

__global__ void __launch_bounds__(BLOCK) rangeloss_kernel(
    const float4* __restrict__ preds4,
    const float4* __restrict__ target4,
    const float*  __restrict__ predsf,
    float* __restrict__ out)
{
    // block covers BLOCK*UNROLL contiguous float4s; lane-contiguous per iteration
    const int base = blockIdx.x * (BLOCK * UNROLL) + threadIdx.x;

    float4 p[UNROLL], t[UNROLL];
    float  pn[UNROLL];

    #pragma unroll
    for (int k = 0; k < UNROLL; ++k) {
        const int i = base + k * BLOCK;
        p[k] = preds4[i];
        t[k] = target4[i];
        // next flat pred element after this float4 (L1 hit: neighbor lane's line).
        // Clamp for the very last float4; unused there (its last element is col 2).
        const int nf = 4 * i + 4;
        pn[k] = predsf[nf < N3 ? nf : 0];
    }

    float sum = 0.0f;

    #pragma unroll
    for (int k = 0; k < UNROLL; ++k) {
        const int i  = base + k * BLOCK;
        const int c0 = (4 * i) % 3;  // column of element 0 of this float4

        const float pe[4]  = {p[k].x, p[k].y, p[k].z, p[k].w};
        const float te[4]  = {t[k].x, t[k].y, t[k].z, t[k].w};
        const float pnx[4] = {p[k].y, p[k].z, p[k].w, pn[k]};  // preds[f+1] per element

        #pragma unroll
        for (int e = 0; e < 4; ++e) {
            int col = c0 + e;                    // 0..5
            col = (col >= 3) ? col - 3 : col;    // mod 3

            const float pp = pe[e], tt = te[e];

            const bool rule02 = (pp < 0.1f && tt == 0.0f) || (pp > 0.9f && tt == 1.0f);
            const bool rule1  = (pnx[e] > 0.9f) || (pp * 1.02f > tt && pp * 0.98f < tt);
            const bool snap   = (col == 1) ? rule1 : rule02;

            const float tn = snap ? pp : tt;
            const float d  = pp - tn;
            sum += d * d;
        }
    }

    sum *= INV_TOTAL;  // pre-scale so the atomic sum is the mean

    // wave-64 butterfly reduce
    #pragma unroll
    for (int off = 32; off > 0; off >>= 1)
        sum += __shfl_down(sum, off, 64);

    __shared__ float smem[BLOCK / 64];
    const int lane = threadIdx.x & 63;
    const int wave = threadIdx.x >> 6;
    if (lane == 0) smem[wave] = sum;
    __syncthreads();

    if (threadIdx.x == 0) {
        atomicAdd(out, smem[0] + smem[1] + smem[2] + smem[3]);
    }
}

extern "C" void kernel_launch(void* const* d_in, const int* in_sizes, int n_in,
                              void* d_out, int out_size, void* d_ws, size_t ws_size,
                              hipStream_t stream)
{
    const float4* preds4  = (const float4*)d_in[0];
    const float4* target4 = (const float4*)d_in[1];
    const float*  predsf  = (const float*)d_in[0];
    float* out = (float*)d_out;

    // d_out is re-poisoned to 0xAA before every timed replay: zero it in-stream.
    hipMemsetAsync(out, 0, sizeof(float), stream);

    const int n_blocks = G4 / (BLOCK * UNROLL);  // 6144, exact
    rangeloss_kernel<<<n_blocks, BLOCK, 0, stream>>>(preds4, target4, predsf, out);
}

// Round 3
// 216.691 us; speedup vs baseline: 1.1806x; 1.0715x over previous
//
#include <hip/hip_runtime.h>

// RangeLoss, two-stage reduction version.
// Round-2 post-mortem: duration tracked atomic count at ~15 ns/atomic
// (8192 atomics -> 121.8us, 6144 -> 94.0us) and was invariant to FETCH_SIZE
// -> same-address atomicAdd serialization was the bottleneck, not memory.
// Stage 1: per-block partial sums to d_ws (no contention).
// Stage 2: one block reduces the 6144 partials and stores out[0].

#define N3      25165824   // 8388608 * 3 floats
#define G4      6291456    // N3 / 4 float4s
#define BLOCK   256
#define UNROLL  4
#define NBLOCKS (G4 / (BLOCK * UNROLL))   // 6144, exact
#define INV_TOTAL (1.0f / 25165824.0f)

__global__ void __launch_bounds__(BLOCK) rangeloss_stage1(
    const float4* __restrict__ preds4,
    const float4* __restrict__ target4,
    const float*  __restrict__ predsf,
    float* __restrict__ partials)
{
    const int base = blockIdx.x * (BLOCK * UNROLL) + threadIdx.x;
    const int lane = threadIdx.x & 63;

    float4 p[UNROLL], t[UNROLL];

    #pragma unroll
    for (int k = 0; k < UNROLL; ++k) {
        const int i = base + k * BLOCK;
        p[k] = preds4[i];
        t[k] = target4[i];
    }

    float sum = 0.0f;

    #pragma unroll
    for (int k = 0; k < UNROLL; ++k) {
        const int i = base + k * BLOCK;

        // preds[4i+4] = next float4's .x. Lanes 0..62 get it from lane+1;
        // lane 63 (wave boundary) loads it (1 line, predicated). Clamp for the
        // very last float4 (unused there: its last element is col 2).
        float pnext = __shfl_down(p[k].x, 1, 64);
        if (lane == 63) {
            const int nf = 4 * i + 4;
            pnext = predsf[nf < N3 ? nf : 0];
        }

        const float pe[4]  = {p[k].x, p[k].y, p[k].z, p[k].w};
        const float te[4]  = {t[k].x, t[k].y, t[k].z, t[k].w};
        const float pnx[4] = {p[k].y, p[k].z, p[k].w, pnext};

        const int c0 = (4 * i) % 3;  // column of element 0 of this float4

        #pragma unroll
        for (int e = 0; e < 4; ++e) {
            int col = c0 + e;
            col = (col >= 3) ? col - 3 : col;    // mod 3

            const float pp = pe[e], tt = te[e];

            const bool rule02 = (pp < 0.1f && tt == 0.0f) || (pp > 0.9f && tt == 1.0f);
            const bool rule1  = (pnx[e] > 0.9f) || (pp * 1.02f > tt && pp * 0.98f < tt);
            const bool snap   = (col == 1) ? rule1 : rule02;

            const float tn = snap ? pp : tt;
            const float d  = pp - tn;
            sum += d * d;
        }
    }

    sum *= INV_TOTAL;  // pre-scale so the summed partials equal the mean

    // wave-64 butterfly reduce
    #pragma unroll
    for (int off = 32; off > 0; off >>= 1)
        sum += __shfl_down(sum, off, 64);

    __shared__ float smem[BLOCK / 64];
    const int wave = threadIdx.x >> 6;
    if (lane == 0) smem[wave] = sum;
    __syncthreads();

    if (threadIdx.x == 0)
        partials[blockIdx.x] = smem[0] + smem[1] + smem[2] + smem[3];
}

__global__ void __launch_bounds__(BLOCK) rangeloss_stage2(
    const float* __restrict__ partials,
    float* __restrict__ out)
{
    float sum = 0.0f;
    for (int i = threadIdx.x; i < NBLOCKS; i += BLOCK)
        sum += partials[i];

    #pragma unroll
    for (int off = 32; off > 0; off >>= 1)
        sum += __shfl_down(sum, off, 64);

    __shared__ float smem[BLOCK / 64];
    const int lane = threadIdx.x & 63;
    const int wave = threadIdx.x >> 6;
    if (lane == 0) smem[wave] = sum;
    __syncthreads();

    if (threadIdx.x == 0)
        out[0] = smem[0] + smem[1] + smem[2] + smem[3];  // overwrites poison
}

extern "C" void kernel_launch(void* const* d_in, const int* in_sizes, int n_in,
                              void* d_out, int out_size, void* d_ws, size_t ws_size,
                              hipStream_t stream)
{
    const float4* preds4  = (const float4*)d_in[0];
    const float4* target4 = (const float4*)d_in[1];
    const float*  predsf  = (const float*)d_in[0];
    float* partials = (float*)d_ws;   // 6144 floats = 24 KB, all written by stage 1
    float* out = (float*)d_out;

    rangeloss_stage1<<<NBLOCKS, BLOCK, 0, stream>>>(preds4, target4, predsf, partials);
    rangeloss_stage2<<<1, BLOCK, 0, stream>>>(partials, out);
}

// Round 5
// 204.641 us; speedup vs baseline: 1.2501x; 1.0589x over previous
//
#include <hip/hip_runtime.h>

// RangeLoss, persistent double-buffered version (R4: fix nontemporal builtin —
// it rejects HIP_vector_type; use a native clang ext_vector_type(4) alias).
// Round-3 post-mortem: one-shot blocks were latency-bound (VALUBusy 20%,
// HBM 17%, nothing saturated) — waves stalled on vmcnt between chunks and
// 6144 block epilogues added dead time. This version: 1536 persistent blocks,
// each processing 4 chunks with explicit register double-buffering (next
// chunk's loads in flight while computing the current one), one epilogue per
// block. Chunk stride is divisible by 3 so per-slot column phase is
// loop-invariant (col logic hoisted out of the hot loop).

#define N3      25165824                  // 8388608 * 3 floats
#define G4      6291456                   // N3 / 4 float4s
#define BLOCK   256
#define UNROLL  4
#define NB      1536                      // persistent blocks (6 per CU)
#define NIT     4                         // G4 / (NB*BLOCK*UNROLL), exact
#define CSTRIDE (NB * BLOCK * UNROLL)     // 1572864, divisible by 3
#define INV_TOTAL (1.0f / 25165824.0f)

typedef float vfloat4 __attribute__((ext_vector_type(4)));  // native vector: ok for nontemporal builtin

struct Chunk {
    vfloat4 p[UNROLL];
    vfloat4 t[UNROLL];
    float   pn[UNROLL];
};

__device__ __forceinline__ void load_chunk(
    Chunk& c, int base,
    const vfloat4* __restrict__ preds4,
    const vfloat4* __restrict__ target4,
    const float*   __restrict__ predsf)
{
    #pragma unroll
    for (int k = 0; k < UNROLL; ++k) {
        const int i = base + k * BLOCK;
        c.p[k] = preds4[i];
        c.t[k] = __builtin_nontemporal_load(&target4[i]);   // read-once stream
        // preds[4i+4] (col-2 neighbor for a col-1 element 3). L1 hit: the same
        // wave's dwordx4 just covered this line. Clamp only matters for the
        // global last float4, whose element 3 is col 2 (value unused).
        c.pn[k] = predsf[min(4 * i + 4, N3 - 1)];
    }
}

__device__ __forceinline__ void compute_chunk(
    const Chunk& c, const bool is_c1[UNROLL][4], float& sum)
{
    #pragma unroll
    for (int k = 0; k < UNROLL; ++k) {
        const float pe[4]  = {c.p[k].x, c.p[k].y, c.p[k].z, c.p[k].w};
        const float te[4]  = {c.t[k].x, c.t[k].y, c.t[k].z, c.t[k].w};
        const float pnx[4] = {c.p[k].y, c.p[k].z, c.p[k].w, c.pn[k]};

        #pragma unroll
        for (int e = 0; e < 4; ++e) {
            const float pp = pe[e], tt = te[e];
            const bool rule02 = (pp < 0.1f && tt == 0.0f) || (pp > 0.9f && tt == 1.0f);
            const bool rule1  = (pnx[e] > 0.9f) || (pp * 1.02f > tt && pp * 0.98f < tt);
            const bool snap   = is_c1[k][e] ? rule1 : rule02;
            // snapped => t' = p => diff is exactly 0
            const float d = snap ? 0.0f : (pp - tt);
            sum += d * d;
        }
    }
}

__global__ void __launch_bounds__(BLOCK) rangeloss_stage1(
    const vfloat4* __restrict__ preds4,
    const vfloat4* __restrict__ target4,
    const float*   __restrict__ predsf,
    float* __restrict__ partials)
{
    const int slot0 = blockIdx.x * (BLOCK * UNROLL) + threadIdx.x;

    // Column phase per slot: element e of float4 i has col (i+e) mod 3.
    // CSTRIDE ≡ 0 (mod 3) -> phase is invariant across outer iterations.
    bool is_c1[UNROLL][4];
    #pragma unroll
    for (int k = 0; k < UNROLL; ++k) {
        const int ph = (slot0 + k * BLOCK) % 3;
        #pragma unroll
        for (int e = 0; e < 4; ++e)
            is_c1[k][e] = ((ph + e) % 3) == 1;
    }

    float sum = 0.0f;
    Chunk A, B;
    load_chunk(A, slot0, preds4, target4, predsf);

    #pragma unroll
    for (int it = 0; it < NIT - 1; ++it) {
        load_chunk(B, slot0 + (it + 1) * CSTRIDE, preds4, target4, predsf);
        compute_chunk(A, is_c1, sum);
        A = B;  // register rename after full unroll
    }
    compute_chunk(A, is_c1, sum);

    sum *= INV_TOTAL;  // pre-scale so summed partials equal the mean

    // wave-64 butterfly reduce
    #pragma unroll
    for (int off = 32; off > 0; off >>= 1)
        sum += __shfl_down(sum, off, 64);

    __shared__ float smem[BLOCK / 64];
    const int lane = threadIdx.x & 63;
    const int wave = threadIdx.x >> 6;
    if (lane == 0) smem[wave] = sum;
    __syncthreads();

    if (threadIdx.x == 0)
        partials[blockIdx.x] = smem[0] + smem[1] + smem[2] + smem[3];
}

__global__ void __launch_bounds__(BLOCK) rangeloss_stage2(
    const float* __restrict__ partials,
    float* __restrict__ out)
{
    float sum = 0.0f;
    for (int i = threadIdx.x; i < NB; i += BLOCK)
        sum += partials[i];

    #pragma unroll
    for (int off = 32; off > 0; off >>= 1)
        sum += __shfl_down(sum, off, 64);

    __shared__ float smem[BLOCK / 64];
    const int lane = threadIdx.x & 63;
    const int wave = threadIdx.x >> 6;
    if (lane == 0) smem[wave] = sum;
    __syncthreads();

    if (threadIdx.x == 0)
        out[0] = smem[0] + smem[1] + smem[2] + smem[3];  // overwrites poison
}

extern "C" void kernel_launch(void* const* d_in, const int* in_sizes, int n_in,
                              void* d_out, int out_size, void* d_ws, size_t ws_size,
                              hipStream_t stream)
{
    const vfloat4* preds4  = (const vfloat4*)d_in[0];
    const vfloat4* target4 = (const vfloat4*)d_in[1];
    const float*   predsf  = (const float*)d_in[0];
    float* partials = (float*)d_ws;   // NB floats = 6 KB, fully written by stage 1
    float* out = (float*)d_out;

    rangeloss_stage1<<<NB, BLOCK, 0, stream>>>(preds4, target4, predsf, partials);
    rangeloss_stage2<<<1, BLOCK, 0, stream>>>(partials, out);
}

// Round 6
// 203.550 us; speedup vs baseline: 1.2568x; 1.0054x over previous
//
#include <hip/hip_runtime.h>

// RangeLoss, R6: force-hoisted loads.
// R5 post-mortem: R3's VGPR_Count=24 proves the compiler SANK the 8 float4
// loads into the compute loop (can't hold 64 regs of data in 24 VGPRs) ->
// one exposed ~500-900cy memory latency per chunk, serially. That explains
// VALUBusy ~20% and duration being invariant to HBM-vs-L3 residency.
// This version: one-shot 6144 WGs (best known), all 12 loads per thread
// issued before ANY compute via sched_barrier(0); uniform up-front pn dword
// load (no divergent lane-63 straggler); rule02 simplified to |p-t|<0.1
// (valid since target is exactly 0.0 or 1.0).

#define N3      25165824                  // 8388608 * 3 floats
#define G4      6291456                   // N3 / 4 float4s
#define BLOCK   256
#define UNROLL  4
#define NB      (G4 / (BLOCK * UNROLL))   // 6144, exact
#define INV_TOTAL (1.0f / 25165824.0f)

typedef float vfloat4 __attribute__((ext_vector_type(4)));

__global__ void __launch_bounds__(BLOCK) rangeloss_stage1(
    const vfloat4* __restrict__ preds4,
    const vfloat4* __restrict__ target4,
    const float*   __restrict__ predsf,
    float* __restrict__ partials)
{
    const int base = blockIdx.x * (BLOCK * UNROLL) + threadIdx.x;

    vfloat4 p[UNROLL], t[UNROLL];
    float   pn[UNROLL];

    // ---- load phase: issue all 12 vmem ops back-to-back ----
    #pragma unroll
    for (int k = 0; k < UNROLL; ++k) {
        const int i = base + k * BLOCK;
        p[k] = preds4[i];
        t[k] = __builtin_nontemporal_load(&target4[i]);   // read-once stream
        // preds[4i+4]: col-2 neighbor for this float4's element 3 (L1 hit —
        // the wave's own dwordx4 just covered that line). min() guards the
        // global last float4, whose element 3 is col 2 (value unused).
        pn[k] = predsf[min(4 * i + 4, N3 - 1)];
    }
    // Do not let the scheduler sink any of the loads past this point.
    __builtin_amdgcn_sched_barrier(0);

    // ---- compute phase ----
    float sum = 0.0f;

    #pragma unroll
    for (int k = 0; k < UNROLL; ++k) {
        const int i  = base + k * BLOCK;
        const int ph = (4 * i) % 3;   // column of element 0

        const float pe[4]  = {p[k].x, p[k].y, p[k].z, p[k].w};
        const float te[4]  = {t[k].x, t[k].y, t[k].z, t[k].w};
        const float pnx[4] = {p[k].y, p[k].z, p[k].w, pn[k]};

        #pragma unroll
        for (int e = 0; e < 4; ++e) {
            int col = ph + e;
            col = (col >= 3) ? col - 3 : col;     // (ph+e) mod 3
            const bool is_c1 = (col == 1);

            const float pp = pe[e], tt = te[e];
            const float diff = pp - tt;

            // col 0/2: snap iff (p<0.1 && t==0)||(p>0.9 && t==1).
            // target is exactly 0.0f or 1.0f -> equivalent to |p-t| < 0.1
            // (abs is a free VOP3 input modifier).
            const bool r02 = fabsf(diff) < 0.1f;
            // col 1: snap iff p_next>0.9 or p within (t/1.02, t/0.98) band
            // (keep the reference's exact arithmetic form for bit-faithfulness).
            const bool inr = (pp * 1.02f > tt) && (pp * 0.98f < tt);
            const bool r1  = (pnx[e] > 0.9f) || inr;

            const bool snap = is_c1 ? r1 : r02;
            const float d = snap ? 0.0f : diff;   // snapped => diff exactly 0
            sum = fmaf(d, d, sum);
        }
    }

    sum *= INV_TOTAL;  // pre-scale so summed partials equal the mean

    // wave-64 butterfly reduce
    #pragma unroll
    for (int off = 32; off > 0; off >>= 1)
        sum += __shfl_down(sum, off, 64);

    __shared__ float smem[BLOCK / 64];
    const int lane = threadIdx.x & 63;
    const int wave = threadIdx.x >> 6;
    if (lane == 0) smem[wave] = sum;
    __syncthreads();

    if (threadIdx.x == 0)
        partials[blockIdx.x] = smem[0] + smem[1] + smem[2] + smem[3];
}

__global__ void __launch_bounds__(BLOCK) rangeloss_stage2(
    const float* __restrict__ partials,
    float* __restrict__ out)
{
    float sum = 0.0f;
    for (int i = threadIdx.x; i < NB; i += BLOCK)
        sum += partials[i];

    #pragma unroll
    for (int off = 32; off > 0; off >>= 1)
        sum += __shfl_down(sum, off, 64);

    __shared__ float smem[BLOCK / 64];
    const int lane = threadIdx.x & 63;
    const int wave = threadIdx.x >> 6;
    if (lane == 0) smem[wave] = sum;
    __syncthreads();

    if (threadIdx.x == 0)
        out[0] = smem[0] + smem[1] + smem[2] + smem[3];  // overwrites poison
}

extern "C" void kernel_launch(void* const* d_in, const int* in_sizes, int n_in,
                              void* d_out, int out_size, void* d_ws, size_t ws_size,
                              hipStream_t stream)
{
    const vfloat4* preds4  = (const vfloat4*)d_in[0];
    const vfloat4* target4 = (const vfloat4*)d_in[1];
    const float*   predsf  = (const float*)d_in[0];
    float* partials = (float*)d_ws;   // NB floats = 24 KB, fully written by stage 1
    float* out = (float*)d_out;

    rangeloss_stage1<<<NB, BLOCK, 0, stream>>>(preds4, target4, predsf, partials);
    rangeloss_stage2<<<1, BLOCK, 0, stream>>>(partials, out);
}

// Round 7
// 201.070 us; speedup vs baseline: 1.2723x; 1.0123x over previous
//
#include <hip/hip_runtime.h>

// RangeLoss, R7: max-TLP streaming.
// R6 post-mortem: hoisting loads pushed stage1 under the harness's own 60us
// fill kernels (6.8 TB/s demonstrated by the memory system). Residual theory:
// long low-occupancy blocks + 4 stride-16B pn gathers/thread (each costs the
// TA ~a full dwordx4). This version: UNROLL=2, 12288 one-shot blocks,
// launch_bounds(256,8) -> 8 waves/SIMD of pure-load TLP; pn loads replaced by
// shfl + 16-float LDS exchange + one 1-lane boundary dword per block.

#define N3      25165824                  // 8388608 * 3 floats
#define G4      6291456                   // N3 / 4 float4s
#define BLOCK   256
#define UNROLL  2
#define NB      (G4 / (BLOCK * UNROLL))   // 12288, exact
#define INV_TOTAL (1.0f / 25165824.0f)

typedef float vfloat4 __attribute__((ext_vector_type(4)));

__global__ void __launch_bounds__(BLOCK, 8) rangeloss_stage1(
    const vfloat4* __restrict__ preds4,
    const vfloat4* __restrict__ target4,
    const float*   __restrict__ predsf,
    float* __restrict__ partials)
{
    const int tid  = threadIdx.x;
    const int lane = tid & 63;
    const int wv   = tid >> 6;
    const int base = blockIdx.x * (BLOCK * UNROLL) + tid;

    // ---- load phase: exactly 4 dwordx4 per thread, back-to-back ----
    vfloat4 p[UNROLL], t[UNROLL];
    #pragma unroll
    for (int k = 0; k < UNROLL; ++k) {
        const int i = base + k * BLOCK;
        p[k] = preds4[i];
        t[k] = __builtin_nontemporal_load(&target4[i]);   // read-once stream
    }

    // block-boundary neighbor: preds element just past this block's range.
    // Only consumed by tid==BLOCK-1 at k==UNROLL-1. 1 lane, 1 line.
    float edge = 0.0f;
    if (tid == BLOCK - 1) {
        const int nf = 4 * (blockIdx.x + 1) * (BLOCK * UNROLL);
        edge = predsf[min(nf, N3 - 1)];   // clamp: global-last element is col 2, unused
    }
    __builtin_amdgcn_sched_barrier(0);

    // ---- p_next exchange (no global pn loads) ----
    // pnext(tid,k) = p.x of float4 (i+1) = p[k].x of tid+1  (tid<255)
    //             = p[k+1].x of tid 0    (tid==255, k<UNROLL-1)
    //             = edge                 (tid==255, k==UNROLL-1)
    __shared__ float xs[4][UNROLL];       // [wave][chunk], lane-0 values
    if (lane == 0) {
        #pragma unroll
        for (int k = 0; k < UNROLL; ++k) xs[wv][k] = p[k].x;
    }
    __syncthreads();

    float pn[UNROLL];
    #pragma unroll
    for (int k = 0; k < UNROLL; ++k) {
        float nx = __shfl_down(p[k].x, 1, 64);            // lanes 0..62
        if (lane == 63) {
            if (wv < 3)                nx = xs[wv + 1][k];            // next wave's lane 0
            else if (k < UNROLL - 1)   nx = xs[0][k + 1];             // tid 0, next chunk
            else                       nx = edge;                     // next block
        }
        pn[k] = nx;
    }

    // ---- compute ----
    float sum = 0.0f;
    #pragma unroll
    for (int k = 0; k < UNROLL; ++k) {
        const int i  = base + k * BLOCK;
        const int ph = i % 3;     // col of element 0 is (4i)%3 = i%3

        const float pe[4]  = {p[k].x, p[k].y, p[k].z, p[k].w};
        const float te[4]  = {t[k].x, t[k].y, t[k].z, t[k].w};
        const float pnx[4] = {p[k].y, p[k].z, p[k].w, pn[k]};

        #pragma unroll
        for (int e = 0; e < 4; ++e) {
            int col = ph + e;
            col = (col >= 3) ? col - 3 : col;             // (ph+e) mod 3
            const bool is_c1 = (col == 1);

            const float pp = pe[e], tt = te[e];
            const float diff = pp - tt;

            // col 0/2: target is exactly 0.0 or 1.0 -> snap iff |p-t| < 0.1
            const bool r02 = __builtin_fabsf(diff) < 0.1f;
            // col 1: snap iff p_next>0.9 or p*1.02>t && p*0.98<t (exact ref form)
            const bool inr = (pp * 1.02f > tt) && (pp * 0.98f < tt);
            const bool r1  = (pnx[e] > 0.9f) || inr;

            const bool snap = is_c1 ? r1 : r02;
            const float d = snap ? 0.0f : diff;           // snapped => diff exactly 0
            sum = fmaf(d, d, sum);
        }
    }

    sum *= INV_TOTAL;  // pre-scale so summed partials equal the mean

    // wave-64 butterfly reduce
    #pragma unroll
    for (int off = 32; off > 0; off >>= 1)
        sum += __shfl_down(sum, off, 64);

    __shared__ float red[BLOCK / 64];
    if (lane == 0) red[wv] = sum;
    __syncthreads();

    if (tid == 0)
        partials[blockIdx.x] = red[0] + red[1] + red[2] + red[3];
}

#define S2BLOCK 1024

__global__ void __launch_bounds__(S2BLOCK) rangeloss_stage2(
    const float* __restrict__ partials,
    float* __restrict__ out)
{
    float sum = 0.0f;
    #pragma unroll
    for (int i = threadIdx.x; i < NB; i += S2BLOCK)
        sum += partials[i];

    #pragma unroll
    for (int off = 32; off > 0; off >>= 1)
        sum += __shfl_down(sum, off, 64);

    __shared__ float smem[S2BLOCK / 64];
    const int lane = threadIdx.x & 63;
    const int wave = threadIdx.x >> 6;
    if (lane == 0) smem[wave] = sum;
    __syncthreads();

    if (threadIdx.x == 0) {
        float s = 0.0f;
        #pragma unroll
        for (int w = 0; w < S2BLOCK / 64; ++w) s += smem[w];
        out[0] = s;  // overwrites poison
    }
}

extern "C" void kernel_launch(void* const* d_in, const int* in_sizes, int n_in,
                              void* d_out, int out_size, void* d_ws, size_t ws_size,
                              hipStream_t stream)
{
    const vfloat4* preds4  = (const vfloat4*)d_in[0];
    const vfloat4* target4 = (const vfloat4*)d_in[1];
    const float*   predsf  = (const float*)d_in[0];
    float* partials = (float*)d_ws;   // NB floats = 48 KB, fully written by stage 1
    float* out = (float*)d_out;

    rangeloss_stage1<<<NB, BLOCK, 0, stream>>>(preds4, target4, predsf, partials);
    rangeloss_stage2<<<1, S2BLOCK, 0, stream>>>(partials, out);
}